// Round 9
// baseline (182.150 us; speedup 1.0000x reference)
//
#include <hip/hip_runtime.h>

#define BLOCK  256
#define NB     2048          // 8 blocks/CU resident
#define CHUNK  1024          // elements per chunk = BLOCK * 4
#define FBLK   1024          // finalize block
#define MAXSEG 2048          // LDS bin capacity (problem: Bseg = 2048)

// Native clang vector types.
typedef float fx4 __attribute__((ext_vector_type(4)));
typedef int   ix4 __attribute__((ext_vector_type(4)));

// Branch-free BCE matching jnp: -(t*clip(log p,-100) + (1-t)*clip(log1p(-p),-100))
__device__ __forceinline__ float bce_elem(float p, float t) {
    float lp  = fmaxf(__logf(p), -100.0f);
    float l1p = fmaxf(__logf(1.0f - p), -100.0f);
    return -__builtin_fmaf(t, lp - l1p, l1p);
}

// Round-9 theory: every 41-43us variant (r0/r1/r2/r8, reg- or DMA-pipelined,
// occ 37-64%) advanced 2048 independent ~47KB fronts -> ~256 interleaved
// streams per HBM channel -> row-buffer thrash caps DRAM at ~1/3 peak. Fill
// (6.6 TB/s) and copy ubench (6.3) advance ONE coherent front. r7 tested the
// coherent sweep but was poisoned by ~320K device atomics (100us even warm).
// This kernel: coherent chunked sweep (chip window = 2048 x 4KB contiguous),
// atomic-free reduction. Each 1024-elem chunk spans <=2 segments (min seg
// ~3650 >> 1024; 47-sigma 3rd segment -> rare global-atomic fallback keeps
// it correct). Two (seg,bce,cnt) entries per chunk, written non-atomically,
// globally sorted by construction; 1-block finalize scans them into LDS bins.
__global__ __launch_bounds__(BLOCK, 8) void stream_kernel(
    const float* __restrict__ pred, const float* __restrict__ tgt,
    const int* __restrict__ batch, const int* __restrict__ mask,
    int* __restrict__ eseg, float* __restrict__ eb, float* __restrict__ ec,
    float* __restrict__ gbins_b, float* __restrict__ gbins_c,
    int n, int nchunks)
{
    const int tid = threadIdx.x;
    const int wid = tid >> 6;

    __shared__ float red[BLOCK / 64][4];

    for (int c = blockIdx.x; c < nchunks; c += NB) {
        const int base = c << 10;                 // c * CHUNK
        const int i4   = (base >> 2) + tid;       // this thread's float4 index
        const int e0   = base + (tid << 2);
        // chunk's first/last segment ids: same-address loads -> cache broadcast
        const int s0   = batch[base];
        const int last = min(base + CHUNK - 1, n - 1);
        const int sL   = batch[last];

        float a0b = 0.f, a0c = 0.f, a1b = 0.f, a1c = 0.f;

        if (e0 + 3 < n) {                         // full float4 (all of N=8M)
            fx4 p = *(reinterpret_cast<const fx4*>(pred)  + i4);
            fx4 t = *(reinterpret_cast<const fx4*>(tgt)   + i4);
            ix4 m = *(reinterpret_cast<const ix4*>(mask)  + i4);
            ix4 s = *(reinterpret_cast<const ix4*>(batch) + i4);
            #pragma unroll
            for (int j = 0; j < 4; ++j) {
                float mf = (float)m[j];
                float v  = bce_elem(p[j] * mf, t[j]);
                int   se = s[j];
                if (se == s0)      { a0b += v; a0c += mf; }
                else if (se == sL) { a1b += v; a1c += mf; }
                else {             // segment wholly inside chunk: ~never; stay correct
                    atomicAdd(&gbins_b[se], v);
                    atomicAdd(&gbins_c[se], mf);
                }
            }
        } else if (e0 < n) {                      // ragged array tail
            for (int j = 0; j < 4 && e0 + j < n; ++j) {
                const int e  = e0 + j;
                float mf = (float)mask[e];
                float v  = bce_elem(pred[e] * mf, tgt[e]);
                int   se = batch[e];
                if (se == s0)      { a0b += v; a0c += mf; }
                else if (se == sL) { a1b += v; a1c += mf; }
                else { atomicAdd(&gbins_b[se], v); atomicAdd(&gbins_c[se], mf); }
            }
        }

        // block-reduce both pairs: wave shfl -> LDS -> thread 0
        #pragma unroll
        for (int o = 32; o > 0; o >>= 1) {
            a0b += __shfl_xor(a0b, o);  a0c += __shfl_xor(a0c, o);
            a1b += __shfl_xor(a1b, o);  a1c += __shfl_xor(a1c, o);
        }
        if ((tid & 63) == 0) {
            red[wid][0] = a0b;  red[wid][1] = a0c;
            red[wid][2] = a1b;  red[wid][3] = a1c;
        }
        __syncthreads();
        if (tid == 0) {
            float sb0 = 0, sc0 = 0, sb1 = 0, sc1 = 0;
            #pragma unroll
            for (int w = 0; w < BLOCK / 64; ++w) {
                sb0 += red[w][0];  sc0 += red[w][1];
                sb1 += red[w][2];  sc1 += red[w][3];
            }
            // entries 2c (s0) and 2c+1 (sL): sorted globally since batch sorted.
            // If sL==s0, entry 2c+1 carries zeros -- harmless.
            eseg[2 * c]     = s0;  eb[2 * c]     = sb0;  ec[2 * c]     = sc0;
            eseg[2 * c + 1] = sL;  eb[2 * c + 1] = sb1;  ec[2 * c + 1] = sc1;
        }
        __syncthreads();                          // red[] reuse safety
    }
}

// 1-block finalize: sorted-entry scan with running accumulator into LDS bins
// (flush on seg change; cross-thread spans merged by LDS atomicAdd), then
// per-graph math + sat term + total sum. Separate dispatch = visibility
// boundary; NO device fences (r3: agent fences on 8-XCD = 5x regression).
__global__ __launch_bounds__(FBLK) void finalize_kernel(
    const int* __restrict__ eseg, const float* __restrict__ eb,
    const float* __restrict__ ec,
    const float* __restrict__ gbins_b, const float* __restrict__ gbins_c,
    const float* __restrict__ sat_pred, const float* __restrict__ sat_tgt,
    float* __restrict__ out, int nentries, int Bseg)
{
    __shared__ float bb[MAXSEG];
    __shared__ float bc[MAXSEG];
    const int tid = threadIdx.x;
    for (int i = tid; i < Bseg; i += FBLK) { bb[i] = 0.f; bc[i] = 0.f; }
    __syncthreads();

    const int per = (nentries + FBLK - 1) / FBLK;
    const int lo  = tid * per;
    const int hi  = min(lo + per, nentries);
    if (lo < hi) {
        int   cur = eseg[lo];
        float ab = 0.f, ac = 0.f;
        for (int i = lo; i < hi; ++i) {
            const int s = eseg[i];
            if (s != cur) {
                atomicAdd(&bb[cur], ab);  atomicAdd(&bc[cur], ac);
                cur = s;  ab = 0.f;  ac = 0.f;
            }
            ab += eb[i];  ac += ec[i];
        }
        atomicAdd(&bb[cur], ab);  atomicAdd(&bc[cur], ac);
    }
    __syncthreads();

    float local = 0.f;
    for (int i = tid; i < Bseg; i += FBLK) {
        const float cnt  = bc[i] + gbins_c[i];     // + rare-fallback bins
        const float bsum = bb[i] + gbins_b[i];
        float pg = (cnt > 0.f) ? bsum / fmaxf(cnt, 1.f) : 0.f;
        pg += bce_elem(sat_pred[i], sat_tgt[i]) * ((1.0f / 50.0f) / (float)Bseg);
        local += pg;
    }
    #pragma unroll
    for (int o = 32; o > 0; o >>= 1) local += __shfl_xor(local, o);
    __shared__ float ws[FBLK / 64];
    if ((tid & 63) == 0) ws[tid >> 6] = local;
    __syncthreads();
    if (tid == 0) {
        float s = 0.f;
        #pragma unroll
        for (int w = 0; w < FBLK / 64; ++w) s += ws[w];
        out[0] = s;
    }
}

extern "C" void kernel_launch(void* const* d_in, const int* in_sizes, int n_in,
                              void* d_out, int out_size, void* d_ws, size_t ws_size,
                              hipStream_t stream) {
    const float* y_mus_pred = (const float*)d_in[0];
    const float* y_mus      = (const float*)d_in[1];
    const float* y_sat_pred = (const float*)d_in[2];
    const float* y_sat      = (const float*)d_in[3];
    const int*   batch      = (const int*)d_in[4];
    const int*   mask       = (const int*)d_in[5];

    const int n    = in_sizes[0];
    const int Bseg = in_sizes[2];

    const int nchunks  = (n + CHUNK - 1) / CHUNK;   // 7813 for N=8M
    const int nentries = 2 * nchunks;

    // workspace layout (~203 KB): entry arrays + rare-fallback global bins
    int*   eseg = (int*)d_ws;
    float* eb   = (float*)(eseg + nentries);
    float* ec   = eb + nentries;
    float* gb   = ec + nentries;
    float* gc   = gb + Bseg;

    hipMemsetAsync(gb, 0, 2 * Bseg * sizeof(float), stream);  // capture-safe
    stream_kernel<<<NB, BLOCK, 0, stream>>>(
        y_mus_pred, y_mus, batch, mask, eseg, eb, ec, gb, gc, n, nchunks);
    finalize_kernel<<<1, FBLK, 0, stream>>>(
        eseg, eb, ec, gb, gc, y_sat_pred, y_sat, (float*)d_out, nentries, Bseg);
}

// Round 10
// 151.227 us; speedup vs baseline: 1.2045x; 1.2045x over previous
//
#include <hip/hip_runtime.h>

#define BLOCK 256

// Native clang vector types (nontemporal builtin rejects HIP_vector_type).
typedef float fx4 __attribute__((ext_vector_type(4)));
typedef int   ix4 __attribute__((ext_vector_type(4)));

// Branch-free BCE matching jnp: -(t*clip(log p,-100) + (1-t)*clip(log1p(-p),-100))
__device__ __forceinline__ float bce_elem(float p, float t) {
    float lp  = fmaxf(__logf(p), -100.0f);
    float l1p = fmaxf(__logf(1.0f - p), -100.0f);
    return -__builtin_fmaf(t, lp - l1p, l1p);
}

// Wave-cooperative lower_bound: first i in [0,n) with a[i] >= v (a ascending).
__device__ __forceinline__ int wave_lower_bound(const int* __restrict__ a, int n, int v) {
    const int lane = threadIdx.x & 63;
    int lo = 0, hi = n;
    while (hi - lo > 64) {
        int range  = hi - lo;
        int stride = range / 65 + 1;
        int idx    = lo + (lane + 1) * stride;
        bool lt    = (idx < hi) && (a[idx] < v);
        int  c     = __popcll(__ballot(lt));
        int  nlo   = lo + c * stride;
        int  nhi   = nlo + stride;
        if (nhi > hi) nhi = hi;
        lo = nlo; hi = nhi;
    }
    int idx = lo + lane;
    bool ge = (idx >= hi) || (a[idx] >= v);
    unsigned long long bal = __ballot(ge);
    return bal ? (lo + __ffsll(bal) - 1) : hi;
}

#define PROC(p, t, m)                                                          \
    do {                                                                       \
        float m0 = (float)(m)[0], m1 = (float)(m)[1],                          \
              m2 = (float)(m)[2], m3 = (float)(m)[3];                          \
        accb += bce_elem((p)[0] * m0, (t)[0]);  accc += m0;                    \
        accb += bce_elem((p)[1] * m1, (t)[1]);  accc += m1;                    \
        accb += bce_elem((p)[2] * m2, (t)[2]);  accc += m2;                    \
        accb += bce_elem((p)[3] * m3, (t)[3]);  accc += m3;                    \
    } while (0)

// r9 established: duration is invariant to HBM-vs-L3 serving (warm replay at
// 0.77MB HBM = same 43us) -> the wall is the on-chip read-serve path, ~2.3-2.9
// TB/s achieved vs ~3.15 (copy ubench read-half). r10 lever: XCD read-locality.
// blockIdx round-robins XCDs, so seg=bid scatters every XCD's L2 across the
// whole 128MB. Swizzle seg=(bid&7)*256+(bid>>3): each XCD streams a contiguous
// ~16MB slab through its own L2/fabric port. Everything else identical to r5
// (best measured: nt loads, 3x unroll, wave search, 2 dispatches, no fences).
__global__ __launch_bounds__(BLOCK, 8) void seg_kernel(
    const float* __restrict__ pred, const float* __restrict__ tgt,
    const int* __restrict__ batch, const int* __restrict__ mask,
    const float* __restrict__ sat_pred, const float* __restrict__ sat_tgt,
    float* __restrict__ per_graph, int n, int Bseg)
{
    const int bid = blockIdx.x;
    // XCD-contiguous segment assignment (Bseg=2048=8*256 exactly; fallback
    // to identity if Bseg isn't a multiple of 8 keeps generality).
    const int b = ((Bseg & 7) == 0) ? ((bid & 7) * (Bseg >> 3) + (bid >> 3))
                                    : bid;
    const int tid = threadIdx.x;

    __shared__ int sh_bounds[2];
    const int wid = tid >> 6;
    if (wid < 2) {                            // wave 0 -> lo, wave 1 -> hi, concurrent
        int r = wave_lower_bound(batch, n, b + wid);
        if ((tid & 63) == 0) sh_bounds[wid] = r;
    }
    __syncthreads();
    const int lo = sh_bounds[0], hi = sh_bounds[1];   // block owns batch range [lo,hi)

    float accb = 0.0f, accc = 0.0f;

    int a0 = (lo + 3) & ~3;                   // first 16B-aligned element
    if (a0 > hi) a0 = hi;
    const int nvec = (hi - a0) >> 2;
    const int a1   = a0 + (nvec << 2);

    // scalar head (<=3 elems)
    for (int i = lo + tid; i < a0; i += BLOCK) {
        float mf = (float)mask[i];
        accb += bce_elem(pred[i] * mf, tgt[i]);
        accc += mf;
    }

    // vector body: 3 coalesced 16B streams, 3x unroll, ALL loads non-temporal.
    const fx4* p4 = reinterpret_cast<const fx4*>(pred) + (a0 >> 2);
    const fx4* t4 = reinterpret_cast<const fx4*>(tgt)  + (a0 >> 2);
    const ix4* m4 = reinterpret_cast<const ix4*>(mask) + (a0 >> 2);

    int i = tid;
    const int nv2 = nvec - 2 * BLOCK;
    for (; i < nv2; i += 3 * BLOCK) {
        fx4 pa = __builtin_nontemporal_load(p4 + i);
        fx4 pb = __builtin_nontemporal_load(p4 + i + BLOCK);
        fx4 pc = __builtin_nontemporal_load(p4 + i + 2 * BLOCK);
        fx4 ta = __builtin_nontemporal_load(t4 + i);
        fx4 tb = __builtin_nontemporal_load(t4 + i + BLOCK);
        fx4 tc = __builtin_nontemporal_load(t4 + i + 2 * BLOCK);
        ix4 ma = __builtin_nontemporal_load(m4 + i);
        ix4 mb = __builtin_nontemporal_load(m4 + i + BLOCK);
        ix4 mc = __builtin_nontemporal_load(m4 + i + 2 * BLOCK);
        PROC(pa, ta, ma);
        PROC(pb, tb, mb);
        PROC(pc, tc, mc);
    }
    for (; i < nvec; i += BLOCK) {            // remainder (<=2 strided iters/thread)
        fx4 p = __builtin_nontemporal_load(p4 + i);
        fx4 t = __builtin_nontemporal_load(t4 + i);
        ix4 m = __builtin_nontemporal_load(m4 + i);
        PROC(p, t, m);
    }

    // scalar tail (<=3 elems)
    for (int k = a1 + tid; k < hi; k += BLOCK) {
        float mf = (float)mask[k];
        accb += bce_elem(pred[k] * mf, tgt[k]);
        accc += mf;
    }

    // block reduction: wave shfl -> LDS -> thread 0
    #pragma unroll
    for (int o = 32; o > 0; o >>= 1) {
        accb += __shfl_xor(accb, o);
        accc += __shfl_xor(accc, o);
    }
    __shared__ float wb[4], wc[4];
    if ((tid & 63) == 0) { wb[tid >> 6] = accb; wc[tid >> 6] = accc; }
    __syncthreads();
    if (tid == 0) {
        float sb = wb[0] + wb[1] + wb[2] + wb[3];
        float sc = wc[0] + wc[1] + wc[2] + wc[3];
        float pg = (sc > 0.0f) ? sb / fmaxf(sc, 1.0f) : 0.0f;
        // fold this graph's share of the sat-BCE mean*L1 term; every b covered once
        pg += bce_elem(sat_pred[b], sat_tgt[b]) * ((1.0f / 50.0f) / (float)Bseg);
        per_graph[b] = pg;                    // plain store: no atomics, no fences
    }
}

__global__ __launch_bounds__(256) void sum_kernel(
    const float* __restrict__ per_graph, float* __restrict__ out, int Bseg)
{
    float local = 0.0f;
    for (int i = threadIdx.x; i < Bseg; i += 256) local += per_graph[i];
    #pragma unroll
    for (int o = 32; o > 0; o >>= 1) local += __shfl_xor(local, o);
    __shared__ float ws[4];
    if ((threadIdx.x & 63) == 0) ws[threadIdx.x >> 6] = local;
    __syncthreads();
    if (threadIdx.x == 0) out[0] = ws[0] + ws[1] + ws[2] + ws[3];
}

extern "C" void kernel_launch(void* const* d_in, const int* in_sizes, int n_in,
                              void* d_out, int out_size, void* d_ws, size_t ws_size,
                              hipStream_t stream) {
    const float* y_mus_pred = (const float*)d_in[0];
    const float* y_mus      = (const float*)d_in[1];
    const float* y_sat_pred = (const float*)d_in[2];
    const float* y_sat      = (const float*)d_in[3];
    const int*   batch      = (const int*)d_in[4];
    const int*   mask       = (const int*)d_in[5];

    const int n    = in_sizes[0];
    const int Bseg = in_sizes[2];

    float* per_graph = (float*)d_ws;   // Bseg floats; every slot written each launch

    seg_kernel<<<Bseg, BLOCK, 0, stream>>>(
        y_mus_pred, y_mus, batch, mask, y_sat_pred, y_sat, per_graph, n, Bseg);
    sum_kernel<<<1, 256, 0, stream>>>(per_graph, (float*)d_out, Bseg);
}